// Round 13
// baseline (341.030 us; speedup 1.0000x reference)
//
#include <hip/hip_runtime.h>

#define N_PTS 786432
#define U_VOX 131072
#define NBLK  (N_PTS/64)

typedef __attribute__((ext_vector_type(8))) short v8s;
typedef __attribute__((ext_vector_type(4))) float v4f;
typedef __attribute__((ext_vector_type(16))) float v16f;

__device__ __forceinline__ unsigned short f2bf(float x){
    unsigned u = __float_as_uint(x);
    u += 0x7fffu + ((u >> 16) & 1u);
    return (unsigned short)(u >> 16);
}
__device__ __forceinline__ unsigned cvtpk(float lo, float hi){
    unsigned r;
    asm("v_cvt_pk_bf16_f32 %0, %1, %2" : "=v"(r) : "v"(lo), "v"(hi));
    return r;
}

// ---- fold BN into weights + pack MFMA layouts (blocks<32) + hist+uidx (all) --
// wp1/wp2: 16x16x32 B-frag layout. wp3/wp4: 32x32x16 A-frag layout
// (lane l holds A[ch = jt*32 + (l&31)][k = ks*16 + (l>>5)*8 + i]).
__global__ __launch_bounds__(256) void k_foldhist(
    const float* __restrict__ bn0, const float* __restrict__ w1,
    const float* __restrict__ b1,  const float* __restrict__ bn2,
    const float* __restrict__ w2,  const float* __restrict__ b2,
    const float* __restrict__ bn5, const float* __restrict__ w3,
    const float* __restrict__ b3,  const float* __restrict__ bn8,
    const float* __restrict__ w4,  const float* __restrict__ wc,
    float* __restrict__ b1ff, float* __restrict__ b2f, float* __restrict__ b3f,
    unsigned short* __restrict__ wp1, unsigned short* __restrict__ wp2,
    unsigned short* __restrict__ wp3, unsigned short* __restrict__ wp4,
    unsigned short* __restrict__ wcp,
    const int* __restrict__ uinv, int* __restrict__ cnt, int* __restrict__ uidx)
{
    int tid = threadIdx.x;
    if (blockIdx.x < 32){
        __shared__ float s0[9],t0[9],s2[64],t2[64],s5[128],t5[128],s8[256],t8[256];
        if (tid < 9){  float g=bn0[tid], b=bn0[9+tid],  m=bn0[18+tid],  v=bn0[27+tid];
            float s=g*rsqrtf(v+1e-5f); s0[tid]=s; t0[tid]=b-m*s; }
        if (tid < 64){ float g=bn2[tid], b=bn2[64+tid], m=bn2[128+tid], v=bn2[192+tid];
            float s=g*rsqrtf(v+1e-5f); s2[tid]=s; t2[tid]=b-m*s; }
        if (tid < 128){float g=bn5[tid], b=bn5[128+tid],m=bn5[256+tid], v=bn5[384+tid];
            float s=g*rsqrtf(v+1e-5f); s5[tid]=s; t5[tid]=b-m*s; }
        { float g=bn8[tid], b=bn8[256+tid], m=bn8[512+tid], v=bn8[768+tid];
            float s=g*rsqrtf(v+1e-5f); s8[tid]=s; t8[tid]=b-m*s; }
        __syncthreads();
        if (blockIdx.x == 0){
            if (tid < 64){ float a=0.f;
                for (int k=0;k<9;k++) a += t0[k]*w1[k*64+tid];
                b1ff[tid]=(a+b1[tid])*s2[tid]+t2[tid]; }
            if (tid<128) b2f[tid]=b2[tid]*s5[tid]+t5[tid];
            b3f[tid]=b3[tid]*s8[tid]+t8[tid];
        }
        const int g0 = blockIdx.x*256 + tid, gstep = 32*256;
        for (int e=g0;e<2048;e+=gstep){          // W1f: 32(K,pad)x64, 16x16 B-frag
            int i=e&7, l=(e>>3)&63, jt=(e>>9)&3;
            int k=((l>>4)<<3)+i, j=jt*16+(l&15);
            wp1[e] = (k<9) ? f2bf(s0[k]*w1[k*64+j]*s2[j]) : (unsigned short)0;
        }
        for (int e=g0;e<8192;e+=gstep){          // W2f: 64x128, 16x16 B-frag
            int i=e&7, l=(e>>3)&63, jt=(e>>9)&7, ks=(e>>12)&1;
            int k=ks*32+((l>>4)<<3)+i, j=jt*16+(l&15);
            wp2[e]=f2bf(w2[k*128+j]*s5[j]);
        }
        for (int e=g0;e<32768;e+=gstep){         // W3f: 128x256, 32x32 A-frag
            int i=e&7, l=(e>>3)&63, jt=(e>>9)&7, ks=(e>>12)&7;
            int k=ks*16+((l>>5)<<3)+i, j=jt*32+(l&31);
            wp3[e]=f2bf(w3[k*256+j]*s8[j]);
        }
        for (int e=g0;e<65536;e+=gstep){         // W4: 256x256, 32x32 A-frag
            int i=e&7, l=(e>>3)&63, jt=(e>>9)&7, ks=(e>>12)&15;
            int k=ks*16+((l>>5)<<3)+i, j=jt*32+(l&31);
            wp4[e]=f2bf(w4[k*256+j]);
        }
        for (int e=g0;e<4096;e+=gstep){          // Wc: 256x16, 16x16 B-frag
            int i=e&7, l=(e>>3)&63, ks=e>>9;
            int k=ks*32+((l>>4)<<3)+i, j=l&15;
            wcp[e]=f2bf(wc[k*16+j]);
        }
    }
    // hist + max-point-index, all 3072 blocks
    int i = blockIdx.x*256 + tid;
    int v = uinv[i];
    atomicAdd(cnt + v, 1);
    atomicMax(uidx + v, i);
}

// ---- counting sort (hierarchical scan) --------------------------------------
__global__ void k_scan1(int* __restrict__ cnt, int* __restrict__ bsum){
    __shared__ int s[256];
    int t=threadIdx.x, i=blockIdx.x*256+t;
    int v=cnt[i]; s[t]=v; __syncthreads();
    for (int off=1;off<256;off<<=1){
        int x=(t>=off)?s[t-off]:0; __syncthreads();
        s[t]+=x; __syncthreads();
    }
    cnt[i]=s[t]-v;
    if (t==255) bsum[blockIdx.x]=s[255];
}
__global__ void k_scan2(int* __restrict__ bsum){
    __shared__ int s[512];
    int t=threadIdx.x;
    int v=bsum[t]; s[t]=v; __syncthreads();
    for (int off=1;off<512;off<<=1){
        int x=(t>=off)?s[t-off]:0; __syncthreads();
        s[t]+=x; __syncthreads();
    }
    bsum[t]=s[t]-v;
}
__global__ void k_scan3u(const int* __restrict__ cnt, const int* __restrict__ bsum,
                         int* __restrict__ cur,
                         const int* __restrict__ unq, float* __restrict__ outf){
    int i=blockIdx.x*256+threadIdx.x;
    cur[i]=cnt[i]+bsum[blockIdx.x];
    int4 u = *(const int4*)(unq + 4*i);
    *(float4*)(outf + 4*i) = make_float4((float)u.x,(float)u.y,(float)u.z,(float)u.w);
}
__global__ __launch_bounds__(256) void k_scatgath(const int* __restrict__ uinv,
    const float* __restrict__ cat, const float* __restrict__ occ,
    int* __restrict__ cur,
    unsigned short* __restrict__ scat16, int* __restrict__ svoxS)
{
    int i = blockIdx.x*256 + threadIdx.x;
    int v = uinv[i];
    int slot = atomicAdd(cur + v, 1);
    const float* src = cat + (size_t)i*9;
    unsigned short tmp[16];
#pragma unroll
    for (int k=0;k<9;k++) tmp[k] = f2bf(src[k]);
    tmp[9] = f2bf(occ[i]);
#pragma unroll
    for (int k=10;k<16;k++) tmp[k]=0;
    uint4* dst = (uint4*)(scat16 + (size_t)slot*16);
    dst[0] = *(uint4*)(tmp);
    dst[1] = *(uint4*)(tmp+8);
    svoxS[slot] = v;
}

// ---- fused MLP: L1/L2 16x16 (r6-proven), L3/L4 32x32x16 (half the MFMA) -----
__global__ __launch_bounds__(256,4) void k_fused(
    const unsigned short* __restrict__ scat16g, const int* __restrict__ svoxS,
    const unsigned short* __restrict__ wp1, const float* __restrict__ b1ff,
    const unsigned short* __restrict__ wp2, const float* __restrict__ b2f,
    const unsigned short* __restrict__ wp3, const float* __restrict__ b3f,
    const unsigned short* __restrict__ wp4, const float* __restrict__ b4,
    unsigned* __restrict__ pooled, unsigned* __restrict__ bpool)
{
    __shared__ __align__(16) char smem[34320];
    int*   svox = (int*)smem;                  // 64
    float* socc = (float*)(smem+256);          // 64
    int*   vpn  = (int*)(smem+512);            // 2
    float* pmlo = (float*)(smem+528);          // 128
    float* pmhi = (float*)(smem+1040);         // 128
    char*  R1   = smem + 1552;                 // 32 KiB overlay region
    char*  sh1  = R1 + 4096;                   // 64x64ch bf16, pitch 128B
    char*  sh2  = R1 + 12288;                  // 64x128ch bf16, pitch 256B

    const int tid = threadIdx.x;
    const int blk = blockIdx.x;
    const int p0  = blk*64;
    const int w = tid>>6, l = tid&63, lane16 = l&15, hi = l>>4;
    const int l31 = l&31, hi2 = l>>5, key32 = (l&7)<<4;

    // ---- stage: scat16 (swizzled) + svox + vpn ----
    if (tid < 128){
        uint4 d = *(const uint4*)(scat16g + (size_t)p0*16 + tid*8);
        int p = tid>>1, q = tid&1;
        *(uint4*)(R1 + p*64 + ((q*16) ^ ((p&3)<<4))) = d;
    } else {
        int t2 = tid-128; int p = t2>>1, q = t2&1;
        *(uint4*)(R1 + p*64 + ((32 + q*16) ^ ((p&3)<<4))) = make_uint4(0,0,0,0);
    }
    if (tid < 64) svox[tid] = svoxS[p0 + tid];
    if (tid == 64) vpn[0] = (p0>0) ? svoxS[p0-1] : -1;
    if (tid == 65) vpn[1] = (p0+64<N_PTS) ? svoxS[p0+64] : -1;
    __syncthreads();
    if (tid < 64){
        unsigned short ob = *(unsigned short*)(R1 + tid*64 + (18 ^ ((tid&3)<<4)));
        socc[tid] = __uint_as_float(((unsigned)ob)<<16);
    }

    // ---- L1 (16x16 MFMA, K=32 padded): wave w -> channels [16w,16w+16) ----
    {
        v4f bias = *(const v4f*)(b1ff + w*16 + 4*hi);
        v8s aw = *(const v8s*)(wp1 + (size_t)(w*64 + l)*8);
        v4f acc1[4];
#pragma unroll
        for (int mt=0;mt<4;mt++){
            int P = mt*16 + lane16;
            v8s act = *(const v8s*)(R1 + P*64 + ((hi*16) ^ ((P&3)<<4)));
            acc1[mt] = __builtin_amdgcn_mfma_f32_16x16x32_bf16(aw, act, bias, 0,0,0);
        }
#pragma unroll
        for (int mt=0;mt<4;mt++){
            int P = mt*16 + lane16, key = (P&7)<<4;
            int cb = (w*16 + 4*hi)*2;
            float v0=fmaxf(acc1[mt][0],0.f), v1=fmaxf(acc1[mt][1],0.f);
            float v2=fmaxf(acc1[mt][2],0.f), v3=fmaxf(acc1[mt][3],0.f);
            *(unsigned*)(sh1 + P*128 + ((cb  )^key)) = cvtpk(v0,v1);
            *(unsigned*)(sh1 + P*128 + ((cb+4)^key)) = cvtpk(v2,v3);
        }
    }
    __syncthreads();

    // ---- L2 (16x16, K=64): wave w -> channels [32w,32w+32) ----
    {
        v4f acc2[4][2];
#pragma unroll
        for (int jj=0;jj<2;jj++){
            v4f bias = *(const v4f*)(b2f + w*32 + jj*16 + 4*hi);
#pragma unroll
            for (int mt=0;mt<4;mt++) acc2[mt][jj]=bias;
        }
#pragma unroll
        for (int ks=0;ks<2;ks++){
            v8s a[4];
#pragma unroll
            for (int mt=0;mt<4;mt++){
                int P = mt*16 + lane16;
                a[mt] = *(const v8s*)(sh1 + P*128 + ((ks*64 + hi*16) ^ ((P&7)<<4)));
            }
#pragma unroll
            for (int jj=0;jj<2;jj++){
                v8s bw = *(const v8s*)(wp2 + (size_t)((ks*8 + w*2 + jj)*64 + l)*8);
#pragma unroll
                for (int mt=0;mt<4;mt++)
                    acc2[mt][jj]=__builtin_amdgcn_mfma_f32_16x16x32_bf16(bw, a[mt], acc2[mt][jj],0,0,0);
            }
        }
#pragma unroll
        for (int mt=0;mt<4;mt++){
            int P = mt*16 + lane16, key = (P&7)<<4;
#pragma unroll
            for (int jj=0;jj<2;jj++){
                int cb = (w*32 + jj*16 + 4*hi)*2;
                float v0=fmaxf(acc2[mt][jj][0],0.f), v1=fmaxf(acc2[mt][jj][1],0.f);
                float v2=fmaxf(acc2[mt][jj][2],0.f), v3=fmaxf(acc2[mt][jj][3],0.f);
                *(unsigned*)(sh2 + P*256 + ((cb  )^key)) = cvtpk(v0,v1);
                *(unsigned*)(sh2 + P*256 + ((cb+4)^key)) = cvtpk(v2,v3);
            }
        }
    }
    __syncthreads();

    // ---- L3 (32x32x16, K=128): wave w -> channels [64w,64w+64) ----
    // D layout: col(point)=l&31, ch = base + 4*hi2 + (reg&3) + 8*(reg>>2)
    {
        v16f acc3[2][2];
#pragma unroll
        for (int jt2=0;jt2<2;jt2++){
            const float* bb = b3f + w*64 + jt2*32 + 4*hi2;
            v4f q0=*(const v4f*)(bb),    q1=*(const v4f*)(bb+8);
            v4f q2=*(const v4f*)(bb+16), q3=*(const v4f*)(bb+24);
            v16f a;
#pragma unroll
            for (int r=0;r<4;r++){ a[r]=q0[r]; a[4+r]=q1[r]; a[8+r]=q2[r]; a[12+r]=q3[r]; }
            acc3[0][jt2]=a; acc3[1][jt2]=a;
        }
#pragma unroll
        for (int ks=0;ks<8;ks++){
            v8s act0 = *(const v8s*)(sh2 + l31*256      + ((ks*32 + hi2*16) ^ key32));
            v8s act1 = *(const v8s*)(sh2 + (32+l31)*256 + ((ks*32 + hi2*16) ^ key32));
            v8s aw0 = *(const v8s*)(wp3 + (size_t)((ks*8 + w*2    )*64 + l)*8);
            v8s aw1 = *(const v8s*)(wp3 + (size_t)((ks*8 + w*2 + 1)*64 + l)*8);
            acc3[0][0]=__builtin_amdgcn_mfma_f32_32x32x16_bf16(aw0, act0, acc3[0][0],0,0,0);
            acc3[0][1]=__builtin_amdgcn_mfma_f32_32x32x16_bf16(aw1, act0, acc3[0][1],0,0,0);
            acc3[1][0]=__builtin_amdgcn_mfma_f32_32x32x16_bf16(aw0, act1, acc3[1][0],0,0,0);
            acc3[1][1]=__builtin_amdgcn_mfma_f32_32x32x16_bf16(aw1, act1, acc3[1][1],0,0,0);
        }
        __syncthreads();           // all sh2 reads done; sh3 overlays R1
#pragma unroll
        for (int mt2=0;mt2<2;mt2++){
            char* rowp = R1 + (mt2*32 + l31)*512;
#pragma unroll
            for (int jt2=0;jt2<2;jt2++){
                int cb0 = (w*64 + jt2*32 + 4*hi2)*2;
                v16f A = acc3[mt2][jt2];
#pragma unroll
                for (int p=0;p<8;p++){
                    const int offs[8]={0,4,16,20,32,36,48,52};
                    *(unsigned*)(rowp + ((cb0 + offs[p]) ^ key32)) =
                        cvtpk(fmaxf(A[2*p],0.f), fmaxf(A[2*p+1],0.f));
                }
            }
        }
    }
    __syncthreads();

    // ---- L4 (32x32x16, K=256): wave w -> channels [64w,64w+64); no relu ----
    {
        v16f acc4[2][2];
#pragma unroll
        for (int jt2=0;jt2<2;jt2++){
            const float* bb = b4 + w*64 + jt2*32 + 4*hi2;
            v4f q0=*(const v4f*)(bb),    q1=*(const v4f*)(bb+8);
            v4f q2=*(const v4f*)(bb+16), q3=*(const v4f*)(bb+24);
            v16f a;
#pragma unroll
            for (int r=0;r<4;r++){ a[r]=q0[r]; a[4+r]=q1[r]; a[8+r]=q2[r]; a[12+r]=q3[r]; }
            acc4[0][jt2]=a; acc4[1][jt2]=a;
        }
#pragma unroll
        for (int ks=0;ks<16;ks++){
            v8s act0 = *(const v8s*)(R1 + l31*512      + ((ks*32 + hi2*16) ^ key32));
            v8s act1 = *(const v8s*)(R1 + (32+l31)*512 + ((ks*32 + hi2*16) ^ key32));
            v8s aw0 = *(const v8s*)(wp4 + (size_t)((ks*8 + w*2    )*64 + l)*8);
            v8s aw1 = *(const v8s*)(wp4 + (size_t)((ks*8 + w*2 + 1)*64 + l)*8);
            acc4[0][0]=__builtin_amdgcn_mfma_f32_32x32x16_bf16(aw0, act0, acc4[0][0],0,0,0);
            acc4[0][1]=__builtin_amdgcn_mfma_f32_32x32x16_bf16(aw1, act0, acc4[0][1],0,0,0);
            acc4[1][0]=__builtin_amdgcn_mfma_f32_32x32x16_bf16(aw0, act1, acc4[1][0],0,0,0);
            acc4[1][1]=__builtin_amdgcn_mfma_f32_32x32x16_bf16(aw1, act1, acc4[1][1],0,0,0);
        }
        __syncthreads();           // all L4 reads done; sh4 overlays R1
#pragma unroll
        for (int mt2=0;mt2<2;mt2++){
            char* rowp = R1 + (mt2*32 + l31)*512;
            float oc = socc[mt2*32 + l31];
#pragma unroll
            for (int jt2=0;jt2<2;jt2++){
                int cb0 = (w*64 + jt2*32 + 4*hi2)*2;
                v16f A = acc4[mt2][jt2];
#pragma unroll
                for (int p=0;p<8;p++){
                    const int offs[8]={0,4,16,20,32,36,48,52};
                    *(unsigned*)(rowp + ((cb0 + offs[p]) ^ key32)) =
                        cvtpk(A[2*p]*oc, A[2*p+1]*oc);
                }
            }
        }
    }
    __syncthreads();

    // ---- split segmented max: waves 0-1 rows 0-31, waves 2-3 rows 32-63 ----
    {
        const int half = tid>>7, c = tid&127, rb = half*32;
        int vl = svox[l];
        int vln = (l<63)? svox[l+1] : (int)0x80000000;
        unsigned long long mask = __ballot((l==63) || (vl!=vln));
        const int vp0=vpn[0], vp1=vpn[1];
        const bool cross = (svox[31]==svox[32]);
        float m0=-3.0e38f, m1=-3.0e38f, d0=0.f, d1=0.f;
        int segStart = rb, dEnd = 0; bool defer=false;
#pragma unroll 8
        for (int k=0;k<32;k++){
            int r = rb + k;
            unsigned x = *(const unsigned*)(R1 + r*512 + ((c*4) ^ ((k&7)<<4)));
            m0 = fmaxf(m0, __uint_as_float(x<<16));
            m1 = fmaxf(m1, __uint_as_float(x & 0xFFFF0000u));
            if ((mask>>r)&1ull){
                int v = svox[r];
                if (half==1 && segStart==32 && cross){
                    defer=true; d0=m0; d1=m1; dEnd=r;
                } else {
                    bool bp = (segStart==0) && (v==vp0);
                    bool bn = (r==63) && (v==vp1);
                    unsigned pk = cvtpk(m0,m1);
                    if (bp) bpool[((size_t)blk*2+0)*128 + c] = pk;
                    if (bn) bpool[((size_t)blk*2+1)*128 + c] = pk;
                    if (!bp && !bn) pooled[(size_t)v*128 + c] = pk;
                }
                m0=-3.0e38f; m1=-3.0e38f; segStart=r+1;
            }
        }
        if (half==0 && !((mask>>31)&1ull)){ pmlo[c]=m0; pmhi[c]=m1; }
        __syncthreads();
        if (defer){
            m0 = fmaxf(d0, pmlo[c]); m1 = fmaxf(d1, pmhi[c]);
            unsigned long long lowm = mask & 0x7FFFFFFFull;
            int ts = lowm ? (64 - __clzll(lowm)) : 0;
            int v = svox[32];
            bool bp = (ts==0) && (v==vp0);
            bool bn = (dEnd==63) && (v==vp1);
            unsigned pk = cvtpk(m0,m1);
            if (bp) bpool[((size_t)blk*2+0)*128 + c] = pk;
            if (bn) bpool[((size_t)blk*2+1)*128 + c] = pk;
            if (!bp && !bn) pooled[(size_t)v*128 + c] = pk;
        }
    }
}

// ---- merge cross-block chains from bpool into pooled ------------------------
__global__ __launch_bounds__(256) void k_bmerge(
    const int* __restrict__ cnt, const int* __restrict__ bsum,
    const int* __restrict__ cur, const unsigned* __restrict__ bpool,
    unsigned* __restrict__ pooled)
{
    int tid = threadIdx.x;
    int c = tid & 127, vv = tid>>7;
    int base = blockIdx.x*16 + vv*8;
#pragma unroll
    for (int i=0;i<8;i++){
        int v = base + i;
        int start = cnt[v] + bsum[v>>8];
        int end   = cur[v];
        int bs = start>>6, be = (end-1)>>6;
        if (bs==be) continue;
        unsigned x = bpool[((size_t)bs*2+1)*128 + c];
        float m0 = __uint_as_float(x<<16);
        float m1 = __uint_as_float(x & 0xFFFF0000u);
        for (int b=bs+1;b<be;b++){
            unsigned y = bpool[((size_t)b*2+1)*128 + c];
            m0 = fmaxf(m0, __uint_as_float(y<<16));
            m1 = fmaxf(m1, __uint_as_float(y & 0xFFFF0000u));
        }
        unsigned z = bpool[((size_t)be*2+0)*128 + c];
        m0 = fmaxf(m0, __uint_as_float(z<<16));
        m1 = fmaxf(m1, __uint_as_float(z & 0xFFFF0000u));
        pooled[(size_t)v*128 + c] = cvtpk(m0,m1);
    }
}

// ---- head (MFMA): relu(pooled@wc+bc)*pooled_occupy; outputs 1 and 2 ---------
__global__ __launch_bounds__(256) void k_head(
    const unsigned short* __restrict__ pooled16,
    const unsigned short* __restrict__ wcp, const float* __restrict__ bc,
    const float* __restrict__ occ, const int* __restrict__ uidx,
    float* __restrict__ outf)
{
    __shared__ float pocc[64];
    int tid=threadIdx.x;
    int v0 = blockIdx.x*64;
    if (tid<64){
        float p = occ[uidx[v0+tid]];
        pocc[tid]=p;
        outf[2621440 + v0 + tid] = p;
    }
    __syncthreads();
    int w=tid>>6, l=tid&63, lane16=l&15, hi=l>>4;
    int vb = w*16;
    float bcj = bc[lane16];
    v4f acc = {bcj,bcj,bcj,bcj};
#pragma unroll
    for (int ks=0;ks<8;ks++){
        v8s a = *(const v8s*)(pooled16 + (size_t)(v0 + vb + lane16)*256 + ks*32 + hi*8);
        v8s b = *(const v8s*)(wcp + (size_t)(ks*64 + l)*8);
        acc = __builtin_amdgcn_mfma_f32_16x16x32_bf16(a, b, acc, 0,0,0);
    }
#pragma unroll
    for (int r=0;r<4;r++){
        int vx = vb + 4*hi + r;
        outf[524288 + (size_t)(v0+vx)*16 + lane16] = fmaxf(acc[r],0.f) * pocc[vx];
    }
}

extern "C" void kernel_launch(void* const* d_in, const int* in_sizes, int n_in,
                              void* d_out, int out_size, void* d_ws, size_t ws_size,
                              hipStream_t stream)
{
    const float* cat =(const float*)d_in[0];
    const float* occ =(const float*)d_in[1];
    const int*   unq =(const int*)  d_in[2];
    const int*   uinv=(const int*)  d_in[3];
    const float* bn0 =(const float*)d_in[4];
    const float* w1  =(const float*)d_in[5];
    const float* b1  =(const float*)d_in[6];
    const float* bn2 =(const float*)d_in[7];
    const float* w2  =(const float*)d_in[8];
    const float* b2  =(const float*)d_in[9];
    const float* bn5 =(const float*)d_in[10];
    const float* w3  =(const float*)d_in[11];
    const float* b3  =(const float*)d_in[12];
    const float* bn8 =(const float*)d_in[13];
    const float* w4  =(const float*)d_in[14];
    const float* b4  =(const float*)d_in[15];
    const float* wc  =(const float*)d_in[16];
    const float* bc  =(const float*)d_in[17];

    // ws layout (~105 MB < proven >=131 MB)
    char* ws = (char*)d_ws;
    unsigned*       pooled = (unsigned*)ws;                       // 64 MiB
    unsigned short* scat16 = (unsigned short*)(ws + 67108864);    // 24 MiB
    int*            svoxS  = (int*)(ws + 92274688);               // 3 MiB
    unsigned*       bpool  = (unsigned*)(ws + 95420416);          // 12 MiB
    int*            cnt    = (int*)(ws + 108003328);              // 512 KiB
    int*            uidx   = (int*)(ws + 108527616);              // 512 KiB
    int*            cur    = (int*)(ws + 109051904);              // 512 KiB
    int*            bsum   = (int*)(ws + 109576192);              // 2 KiB
    float*          b1ff   = (float*)(ws + 109578240);
    float*          b2f    = (float*)(ws + 109578496);
    float*          b3f    = (float*)(ws + 109579008);
    unsigned short* wp1    = (unsigned short*)(ws + 109580032);
    unsigned short* wp2    = (unsigned short*)(ws + 109584128);
    unsigned short* wp3    = (unsigned short*)(ws + 109600512);
    unsigned short* wp4    = (unsigned short*)(ws + 109666048);
    unsigned short* wcp    = (unsigned short*)(ws + 109797120);

    float* outf = (float*)d_out;

    // cnt (atomicAdd) and uidx (atomicMax) live in never-re-poisoned ws -> zero
    // them every call (round-5 lesson). Contiguous: one 1 MiB memset.
    hipMemsetAsync((void*)cnt, 0, 1048576, stream);
    k_foldhist<<<N_PTS/256, 256,0,stream>>>(bn0,w1,b1,bn2,w2,b2,bn5,w3,b3,bn8,w4,wc,
                                            b1ff,b2f,b3f,wp1,wp2,wp3,wp4,wcp,
                                            uinv,cnt,uidx);
    k_scan1   <<<U_VOX/256, 256,0,stream>>>(cnt,bsum);
    k_scan2   <<<1,         512,0,stream>>>(bsum);
    k_scan3u  <<<U_VOX/256, 256,0,stream>>>(cnt,bsum,cur,unq,outf);
    k_scatgath<<<N_PTS/256, 256,0,stream>>>(uinv,cat,occ,cur,scat16,svoxS);
    k_fused   <<<NBLK,      256,0,stream>>>(scat16,svoxS,wp1,b1ff,wp2,b2f,
                                            wp3,b3f,wp4,b4,pooled,bpool);
    k_bmerge  <<<U_VOX/16,  256,0,stream>>>(cnt,bsum,cur,bpool,pooled);
    k_head    <<<U_VOX/64,  256,0,stream>>>((unsigned short*)pooled,wcp,bc,occ,uidx,outf);
}

// Round 14
// 327.718 us; speedup vs baseline: 1.0406x; 1.0406x over previous
//
#include <hip/hip_runtime.h>

#define N_PTS 786432
#define U_VOX 131072
#define NBLK  (N_PTS/64)

typedef __attribute__((ext_vector_type(8))) short v8s;
typedef __attribute__((ext_vector_type(4))) float v4f;

__device__ __forceinline__ unsigned short f2bf(float x){
    unsigned u = __float_as_uint(x);
    u += 0x7fffu + ((u >> 16) & 1u);
    return (unsigned short)(u >> 16);
}
__device__ __forceinline__ unsigned cvtpk(float lo, float hi){
    unsigned r;
    asm("v_cvt_pk_bf16_f32 %0, %1, %2" : "=v"(r) : "v"(lo), "v"(hi));
    return r;
}

// ---- fold BN into weights + pack MFMA layouts (blocks<32) + hist+uidx (all) --
__global__ __launch_bounds__(256) void k_foldhist(
    const float* __restrict__ bn0, const float* __restrict__ w1,
    const float* __restrict__ b1,  const float* __restrict__ bn2,
    const float* __restrict__ w2,  const float* __restrict__ b2,
    const float* __restrict__ bn5, const float* __restrict__ w3,
    const float* __restrict__ b3,  const float* __restrict__ bn8,
    const float* __restrict__ w4,  const float* __restrict__ wc,
    float* __restrict__ b1ff, float* __restrict__ b2f, float* __restrict__ b3f,
    unsigned short* __restrict__ wp1, unsigned short* __restrict__ wp2,
    unsigned short* __restrict__ wp3, unsigned short* __restrict__ wp4,
    unsigned short* __restrict__ wcp,
    const int* __restrict__ uinv, int* __restrict__ cnt, int* __restrict__ uidx)
{
    int tid = threadIdx.x;
    if (blockIdx.x < 32){
        __shared__ float s0[9],t0[9],s2[64],t2[64],s5[128],t5[128],s8[256],t8[256];
        if (tid < 9){  float g=bn0[tid], b=bn0[9+tid],  m=bn0[18+tid],  v=bn0[27+tid];
            float s=g*rsqrtf(v+1e-5f); s0[tid]=s; t0[tid]=b-m*s; }
        if (tid < 64){ float g=bn2[tid], b=bn2[64+tid], m=bn2[128+tid], v=bn2[192+tid];
            float s=g*rsqrtf(v+1e-5f); s2[tid]=s; t2[tid]=b-m*s; }
        if (tid < 128){float g=bn5[tid], b=bn5[128+tid],m=bn5[256+tid], v=bn5[384+tid];
            float s=g*rsqrtf(v+1e-5f); s5[tid]=s; t5[tid]=b-m*s; }
        { float g=bn8[tid], b=bn8[256+tid], m=bn8[512+tid], v=bn8[768+tid];
            float s=g*rsqrtf(v+1e-5f); s8[tid]=s; t8[tid]=b-m*s; }
        __syncthreads();
        if (blockIdx.x == 0){
            if (tid < 64){ float a=0.f;
                for (int k=0;k<9;k++) a += t0[k]*w1[k*64+tid];
                b1ff[tid]=(a+b1[tid])*s2[tid]+t2[tid]; }
            if (tid<128) b2f[tid]=b2[tid]*s5[tid]+t5[tid];
            b3f[tid]=b3[tid]*s8[tid]+t8[tid];
        }
        const int g0 = blockIdx.x*256 + tid, gstep = 32*256;
        for (int e=g0;e<2048;e+=gstep){          // W1f: 32(K,pad)x64, NT=4
            int i=e&7, l=(e>>3)&63, jt=(e>>9)&3;
            int k=((l>>4)<<3)+i, j=jt*16+(l&15);
            wp1[e] = (k<9) ? f2bf(s0[k]*w1[k*64+j]*s2[j]) : (unsigned short)0;
        }
        for (int e=g0;e<8192;e+=gstep){          // W2f: 64x128, NT=8
            int i=e&7, l=(e>>3)&63, jt=(e>>9)&7, ks=(e>>12)&1;
            int k=ks*32+((l>>4)<<3)+i, j=jt*16+(l&15);
            wp2[e]=f2bf(w2[k*128+j]*s5[j]);
        }
        for (int e=g0;e<32768;e+=gstep){         // W3f: 128x256, NT=16
            int i=e&7, l=(e>>3)&63, jt=(e>>9)&15, ks=e>>13;
            int k=ks*32+((l>>4)<<3)+i, j=jt*16+(l&15);
            wp3[e]=f2bf(w3[k*256+j]*s8[j]);
        }
        for (int e=g0;e<65536;e+=gstep){         // W4: 256x256, NT=16
            int i=e&7, l=(e>>3)&63, jt=(e>>9)&15, ks=e>>13;
            int k=ks*32+((l>>4)<<3)+i, j=jt*16+(l&15);
            wp4[e]=f2bf(w4[k*256+j]);
        }
        for (int e=g0;e<4096;e+=gstep){          // Wc: 256x16, NT=1
            int i=e&7, l=(e>>3)&63, ks=e>>9;
            int k=ks*32+((l>>4)<<3)+i, j=l&15;
            wcp[e]=f2bf(wc[k*16+j]);
        }
    }
    // hist + max-point-index, all 3072 blocks
    int i = blockIdx.x*256 + tid;
    int v = uinv[i];
    atomicAdd(cnt + v, 1);
    atomicMax(uidx + v, i);
}

// ---- counting sort (hierarchical scan) --------------------------------------
__global__ void k_scan1(int* __restrict__ cnt, int* __restrict__ bsum){
    __shared__ int s[256];
    int t=threadIdx.x, i=blockIdx.x*256+t;
    int v=cnt[i]; s[t]=v; __syncthreads();
    for (int off=1;off<256;off<<=1){
        int x=(t>=off)?s[t-off]:0; __syncthreads();
        s[t]+=x; __syncthreads();
    }
    cnt[i]=s[t]-v;
    if (t==255) bsum[blockIdx.x]=s[255];
}
__global__ void k_scan2(int* __restrict__ bsum){
    __shared__ int s[512];
    int t=threadIdx.x;
    int v=bsum[t]; s[t]=v; __syncthreads();
    for (int off=1;off<512;off<<=1){
        int x=(t>=off)?s[t-off]:0; __syncthreads();
        s[t]+=x; __syncthreads();
    }
    bsum[t]=s[t]-v;
}
// scan3 + unq pass-through fused (both per-element, independent)
__global__ void k_scan3u(const int* __restrict__ cnt, const int* __restrict__ bsum,
                         int* __restrict__ cur,
                         const int* __restrict__ unq, float* __restrict__ outf){
    int i=blockIdx.x*256+threadIdx.x;
    cur[i]=cnt[i]+bsum[blockIdx.x];
    int4 u = *(const int4*)(unq + 4*i);
    *(float4*)(outf + 4*i) = make_float4((float)u.x,(float)u.y,(float)u.z,(float)u.w);
}
__global__ __launch_bounds__(256) void k_scatgath(const int* __restrict__ uinv,
    const float* __restrict__ cat, const float* __restrict__ occ,
    int* __restrict__ cur,
    unsigned short* __restrict__ scat16, int* __restrict__ svoxS)
{
    int i = blockIdx.x*256 + threadIdx.x;
    int v = uinv[i];
    int slot = atomicAdd(cur + v, 1);
    const float* src = cat + (size_t)i*9;
    unsigned short tmp[16];
#pragma unroll
    for (int k=0;k<9;k++) tmp[k] = f2bf(src[k]);
    tmp[9] = f2bf(occ[i]);
#pragma unroll
    for (int k=10;k<16;k++) tmp[k]=0;
    uint4* dst = (uint4*)(scat16 + (size_t)slot*16);
    dst[0] = *(uint4*)(tmp);
    dst[1] = *(uint4*)(tmp+8);
    svoxS[slot] = v;
}

// ---- fused MLP — BYTE-IDENTICAL to rounds 6/10/12 (208.5 us, proven 3x) -----
__global__ __launch_bounds__(256,4) void k_fused(
    const unsigned short* __restrict__ scat16g, const int* __restrict__ svoxS,
    const unsigned short* __restrict__ wp1, const float* __restrict__ b1ff,
    const unsigned short* __restrict__ wp2, const float* __restrict__ b2f,
    const unsigned short* __restrict__ wp3, const float* __restrict__ b3f,
    const unsigned short* __restrict__ wp4, const float* __restrict__ b4,
    unsigned* __restrict__ pooled, unsigned* __restrict__ bpool)
{
    __shared__ __align__(16) char smem[34320];
    int*   svox = (int*)smem;                  // 64
    float* socc = (float*)(smem+256);          // 64
    int*   vpn  = (int*)(smem+512);            // 2
    float* pmlo = (float*)(smem+528);          // 128
    float* pmhi = (float*)(smem+1040);         // 128
    char*  R1   = smem + 1552;                 // 32 KiB overlay region
    char*  sh1  = R1 + 4096;                   // 64x64ch bf16, pitch 128B
    char*  sh2  = R1 + 12288;                  // 64x128ch bf16, pitch 256B

    const int tid = threadIdx.x;
    const int blk = blockIdx.x;
    const int p0  = blk*64;
    const int w = tid>>6, l = tid&63, lane16 = l&15, hi = l>>4;

    // ---- stage: scat16 (swizzled) + svox + vpn ----
    if (tid < 128){
        uint4 d = *(const uint4*)(scat16g + (size_t)p0*16 + tid*8);
        int p = tid>>1, q = tid&1;
        *(uint4*)(R1 + p*64 + ((q*16) ^ ((p&3)<<4))) = d;
    } else {
        int t2 = tid-128; int p = t2>>1, q = t2&1;
        *(uint4*)(R1 + p*64 + ((32 + q*16) ^ ((p&3)<<4))) = make_uint4(0,0,0,0);
    }
    if (tid < 64) svox[tid] = svoxS[p0 + tid];
    if (tid == 64) vpn[0] = (p0>0) ? svoxS[p0-1] : -1;
    if (tid == 65) vpn[1] = (p0+64<N_PTS) ? svoxS[p0+64] : -1;
    __syncthreads();
    if (tid < 64){
        unsigned short ob = *(unsigned short*)(R1 + tid*64 + (18 ^ ((tid&3)<<4)));
        socc[tid] = __uint_as_float(((unsigned)ob)<<16);
    }

    // ---- L1 (MFMA, K=32 padded): wave w -> channels [16w,16w+16) ----
    {
        v4f bias = *(const v4f*)(b1ff + w*16 + 4*hi);
        v8s aw = *(const v8s*)(wp1 + (size_t)(w*64 + l)*8);
        v4f acc1[4];
#pragma unroll
        for (int mt=0;mt<4;mt++){
            int P = mt*16 + lane16;
            v8s act = *(const v8s*)(R1 + P*64 + ((hi*16) ^ ((P&3)<<4)));
            acc1[mt] = __builtin_amdgcn_mfma_f32_16x16x32_bf16(aw, act, bias, 0,0,0);
        }
#pragma unroll
        for (int mt=0;mt<4;mt++){
            int P = mt*16 + lane16, key = (P&7)<<4;
            int cb = (w*16 + 4*hi)*2;
            float v0=fmaxf(acc1[mt][0],0.f), v1=fmaxf(acc1[mt][1],0.f);
            float v2=fmaxf(acc1[mt][2],0.f), v3=fmaxf(acc1[mt][3],0.f);
            *(unsigned*)(sh1 + P*128 + ((cb  )^key)) = cvtpk(v0,v1);
            *(unsigned*)(sh1 + P*128 + ((cb+4)^key)) = cvtpk(v2,v3);
        }
    }
    __syncthreads();

    // ---- L2 (K=64): wave w -> channels [32w,32w+32) ----
    {
        v4f acc2[4][2];
#pragma unroll
        for (int jj=0;jj<2;jj++){
            v4f bias = *(const v4f*)(b2f + w*32 + jj*16 + 4*hi);
#pragma unroll
            for (int mt=0;mt<4;mt++) acc2[mt][jj]=bias;
        }
#pragma unroll
        for (int ks=0;ks<2;ks++){
            v8s a[4];
#pragma unroll
            for (int mt=0;mt<4;mt++){
                int P = mt*16 + lane16;
                a[mt] = *(const v8s*)(sh1 + P*128 + ((ks*64 + hi*16) ^ ((P&7)<<4)));
            }
#pragma unroll
            for (int jj=0;jj<2;jj++){
                v8s bw = *(const v8s*)(wp2 + (size_t)((ks*8 + w*2 + jj)*64 + l)*8);
#pragma unroll
                for (int mt=0;mt<4;mt++)
                    acc2[mt][jj]=__builtin_amdgcn_mfma_f32_16x16x32_bf16(bw, a[mt], acc2[mt][jj],0,0,0);
            }
        }
#pragma unroll
        for (int mt=0;mt<4;mt++){
            int P = mt*16 + lane16, key = (P&7)<<4;
#pragma unroll
            for (int jj=0;jj<2;jj++){
                int cb = (w*32 + jj*16 + 4*hi)*2;
                float v0=fmaxf(acc2[mt][jj][0],0.f), v1=fmaxf(acc2[mt][jj][1],0.f);
                float v2=fmaxf(acc2[mt][jj][2],0.f), v3=fmaxf(acc2[mt][jj][3],0.f);
                *(unsigned*)(sh2 + P*256 + ((cb  )^key)) = cvtpk(v0,v1);
                *(unsigned*)(sh2 + P*256 + ((cb+4)^key)) = cvtpk(v2,v3);
            }
        }
    }
    __syncthreads();

    // ---- L3 (K=128): wave w -> channels [64w,64w+64) ----
    {
        v4f acc3[4][4];
#pragma unroll
        for (int jj=0;jj<4;jj++){
            v4f bias = *(const v4f*)(b3f + w*64 + jj*16 + 4*hi);
#pragma unroll
            for (int mt=0;mt<4;mt++) acc3[mt][jj]=bias;
        }
#pragma unroll
        for (int ks=0;ks<4;ks++){
            v8s a[4];
#pragma unroll
            for (int mt=0;mt<4;mt++){
                int P = mt*16 + lane16;
                a[mt] = *(const v8s*)(sh2 + P*256 + ((ks*64 + hi*16) ^ ((P&7)<<4)));
            }
#pragma unroll
            for (int jj=0;jj<4;jj++){
                v8s bw = *(const v8s*)(wp3 + (size_t)((ks*16 + w*4 + jj)*64 + l)*8);
#pragma unroll
                for (int mt=0;mt<4;mt++)
                    acc3[mt][jj]=__builtin_amdgcn_mfma_f32_16x16x32_bf16(bw, a[mt], acc3[mt][jj],0,0,0);
            }
        }
        __syncthreads();           // all sh2 reads done; sh3 overlays R1
#pragma unroll
        for (int mt=0;mt<4;mt++){
            int P = mt*16 + lane16, key = (P&7)<<4;
#pragma unroll
            for (int jj=0;jj<4;jj++){
                int cb = (w*64 + jj*16 + 4*hi)*2;
                float v0=fmaxf(acc3[mt][jj][0],0.f), v1=fmaxf(acc3[mt][jj][1],0.f);
                float v2=fmaxf(acc3[mt][jj][2],0.f), v3=fmaxf(acc3[mt][jj][3],0.f);
                *(unsigned*)(R1 + P*512 + ((cb  )^key)) = cvtpk(v0,v1);
                *(unsigned*)(R1 + P*512 + ((cb+4)^key)) = cvtpk(v2,v3);
            }
        }
    }
    __syncthreads();

    // ---- L4 (K=256): wave w -> channels [64w,64w+64); no relu ----
    {
        v4f acc4[4][4];
#pragma unroll
        for (int jj=0;jj<4;jj++){
            v4f bias = *(const v4f*)(b4 + w*64 + jj*16 + 4*hi);
#pragma unroll
            for (int mt=0;mt<4;mt++) acc4[mt][jj]=bias;
        }
#pragma unroll
        for (int ks=0;ks<8;ks++){
            v8s a[4];
#pragma unroll
            for (int mt=0;mt<4;mt++){
                int P = mt*16 + lane16;
                a[mt] = *(const v8s*)(R1 + P*512 + ((ks*64 + hi*16) ^ ((P&7)<<4)));
            }
#pragma unroll
            for (int jj=0;jj<4;jj++){
                v8s bw = *(const v8s*)(wp4 + (size_t)((ks*16 + w*4 + jj)*64 + l)*8);
#pragma unroll
                for (int mt=0;mt<4;mt++)
                    acc4[mt][jj]=__builtin_amdgcn_mfma_f32_16x16x32_bf16(bw, a[mt], acc4[mt][jj],0,0,0);
            }
        }
        __syncthreads();           // all sh3 reads done; sh4 overlays R1
#pragma unroll
        for (int mt=0;mt<4;mt++){
            int P = mt*16 + lane16, key = (P&7)<<4;
            float oc = socc[P];
#pragma unroll
            for (int jj=0;jj<4;jj++){
                int cb = (w*64 + jj*16 + 4*hi)*2;
                *(unsigned*)(R1 + P*512 + ((cb  )^key)) = cvtpk(acc4[mt][jj][0]*oc, acc4[mt][jj][1]*oc);
                *(unsigned*)(R1 + P*512 + ((cb+4)^key)) = cvtpk(acc4[mt][jj][2]*oc, acc4[mt][jj][3]*oc);
            }
        }
    }
    __syncthreads();

    // ---- split segmented max: waves 0-1 rows 0-31, waves 2-3 rows 32-63 ----
    {
        const int half = tid>>7, c = tid&127, rb = half*32;
        int vl = svox[l];
        int vln = (l<63)? svox[l+1] : (int)0x80000000;
        unsigned long long mask = __ballot((l==63) || (vl!=vln));
        const int vp0=vpn[0], vp1=vpn[1];
        const bool cross = (svox[31]==svox[32]);
        float m0=-3.0e38f, m1=-3.0e38f, d0=0.f, d1=0.f;
        int segStart = rb, dEnd = 0; bool defer=false;
#pragma unroll 8
        for (int k=0;k<32;k++){
            int r = rb + k;
            unsigned x = *(const unsigned*)(R1 + r*512 + ((c*4) ^ ((k&7)<<4)));
            m0 = fmaxf(m0, __uint_as_float(x<<16));
            m1 = fmaxf(m1, __uint_as_float(x & 0xFFFF0000u));
            if ((mask>>r)&1ull){
                int v = svox[r];
                if (half==1 && segStart==32 && cross){
                    defer=true; d0=m0; d1=m1; dEnd=r;
                } else {
                    bool bp = (segStart==0) && (v==vp0);
                    bool bn = (r==63) && (v==vp1);
                    unsigned pk = cvtpk(m0,m1);
                    if (bp) bpool[((size_t)blk*2+0)*128 + c] = pk;
                    if (bn) bpool[((size_t)blk*2+1)*128 + c] = pk;
                    if (!bp && !bn) pooled[(size_t)v*128 + c] = pk;
                }
                m0=-3.0e38f; m1=-3.0e38f; segStart=r+1;
            }
        }
        if (half==0 && !((mask>>31)&1ull)){ pmlo[c]=m0; pmhi[c]=m1; }
        __syncthreads();
        if (defer){
            m0 = fmaxf(d0, pmlo[c]); m1 = fmaxf(d1, pmhi[c]);
            unsigned long long lowm = mask & 0x7FFFFFFFull;
            int ts = lowm ? (64 - __clzll(lowm)) : 0;
            int v = svox[32];
            bool bp = (ts==0) && (v==vp0);
            bool bn = (dEnd==63) && (v==vp1);
            unsigned pk = cvtpk(m0,m1);
            if (bp) bpool[((size_t)blk*2+0)*128 + c] = pk;
            if (bn) bpool[((size_t)blk*2+1)*128 + c] = pk;
            if (!bp && !bn) pooled[(size_t)v*128 + c] = pk;
        }
    }
}

// ---- merge cross-block chains from bpool into pooled ------------------------
__global__ __launch_bounds__(256) void k_bmerge(
    const int* __restrict__ cnt, const int* __restrict__ bsum,
    const int* __restrict__ cur, const unsigned* __restrict__ bpool,
    unsigned* __restrict__ pooled)
{
    int tid = threadIdx.x;
    int c = tid & 127, vv = tid>>7;
    int base = blockIdx.x*16 + vv*8;
#pragma unroll
    for (int i=0;i<8;i++){
        int v = base + i;
        int start = cnt[v] + bsum[v>>8];
        int end   = cur[v];
        int bs = start>>6, be = (end-1)>>6;
        if (bs==be) continue;
        unsigned x = bpool[((size_t)bs*2+1)*128 + c];
        float m0 = __uint_as_float(x<<16);
        float m1 = __uint_as_float(x & 0xFFFF0000u);
        for (int b=bs+1;b<be;b++){
            unsigned y = bpool[((size_t)b*2+1)*128 + c];
            m0 = fmaxf(m0, __uint_as_float(y<<16));
            m1 = fmaxf(m1, __uint_as_float(y & 0xFFFF0000u));
        }
        unsigned z = bpool[((size_t)be*2+0)*128 + c];
        m0 = fmaxf(m0, __uint_as_float(z<<16));
        m1 = fmaxf(m1, __uint_as_float(z & 0xFFFF0000u));
        pooled[(size_t)v*128 + c] = cvtpk(m0,m1);
    }
}

// ---- head (MFMA): relu(pooled@wc+bc)*pooled_occupy; outputs 1 and 2 ---------
__global__ __launch_bounds__(256) void k_head(
    const unsigned short* __restrict__ pooled16,
    const unsigned short* __restrict__ wcp, const float* __restrict__ bc,
    const float* __restrict__ occ, const int* __restrict__ uidx,
    float* __restrict__ outf)
{
    __shared__ float pocc[64];
    int tid=threadIdx.x;
    int v0 = blockIdx.x*64;
    if (tid<64){
        float p = occ[uidx[v0+tid]];
        pocc[tid]=p;
        outf[2621440 + v0 + tid] = p;
    }
    __syncthreads();
    int w=tid>>6, l=tid&63, lane16=l&15, hi=l>>4;
    int vb = w*16;
    float bcj = bc[lane16];
    v4f acc = {bcj,bcj,bcj,bcj};
#pragma unroll
    for (int ks=0;ks<8;ks++){
        v8s a = *(const v8s*)(pooled16 + (size_t)(v0 + vb + lane16)*256 + ks*32 + hi*8);
        v8s b = *(const v8s*)(wcp + (size_t)(ks*64 + l)*8);
        acc = __builtin_amdgcn_mfma_f32_16x16x32_bf16(a, b, acc, 0,0,0);
    }
#pragma unroll
    for (int r=0;r<4;r++){
        int vx = vb + 4*hi + r;
        outf[524288 + (size_t)(v0+vx)*16 + lane16] = fmaxf(acc[r],0.f) * pocc[vx];
    }
}

extern "C" void kernel_launch(void* const* d_in, const int* in_sizes, int n_in,
                              void* d_out, int out_size, void* d_ws, size_t ws_size,
                              hipStream_t stream)
{
    const float* cat =(const float*)d_in[0];
    const float* occ =(const float*)d_in[1];
    const int*   unq =(const int*)  d_in[2];
    const int*   uinv=(const int*)  d_in[3];
    const float* bn0 =(const float*)d_in[4];
    const float* w1  =(const float*)d_in[5];
    const float* b1  =(const float*)d_in[6];
    const float* bn2 =(const float*)d_in[7];
    const float* w2  =(const float*)d_in[8];
    const float* b2  =(const float*)d_in[9];
    const float* bn5 =(const float*)d_in[10];
    const float* w3  =(const float*)d_in[11];
    const float* b3  =(const float*)d_in[12];
    const float* bn8 =(const float*)d_in[13];
    const float* w4  =(const float*)d_in[14];
    const float* b4  =(const float*)d_in[15];
    const float* wc  =(const float*)d_in[16];
    const float* bc  =(const float*)d_in[17];

    // ws layout (~105 MB < proven >=131 MB)
    char* ws = (char*)d_ws;
    unsigned*       pooled = (unsigned*)ws;                       // 64 MiB
    unsigned short* scat16 = (unsigned short*)(ws + 67108864);    // 24 MiB
    int*            svoxS  = (int*)(ws + 92274688);               // 3 MiB
    unsigned*       bpool  = (unsigned*)(ws + 95420416);          // 12 MiB
    int*            cnt    = (int*)(ws + 108003328);              // 512 KiB
    int*            uidx   = (int*)(ws + 108527616);              // 512 KiB
    int*            cur    = (int*)(ws + 109051904);              // 512 KiB
    int*            bsum   = (int*)(ws + 109576192);              // 2 KiB
    float*          b1ff   = (float*)(ws + 109578240);
    float*          b2f    = (float*)(ws + 109578496);
    float*          b3f    = (float*)(ws + 109579008);
    unsigned short* wp1    = (unsigned short*)(ws + 109580032);
    unsigned short* wp2    = (unsigned short*)(ws + 109584128);
    unsigned short* wp3    = (unsigned short*)(ws + 109600512);
    unsigned short* wp4    = (unsigned short*)(ws + 109666048);
    unsigned short* wcp    = (unsigned short*)(ws + 109797120);

    float* outf = (float*)d_out;

    // cnt (atomicAdd) and uidx (atomicMax) live in never-re-poisoned ws -> zero
    // them every call (round-5 lesson). Contiguous: one 1 MiB memset.
    hipMemsetAsync((void*)cnt, 0, 1048576, stream);
    k_foldhist<<<N_PTS/256, 256,0,stream>>>(bn0,w1,b1,bn2,w2,b2,bn5,w3,b3,bn8,w4,wc,
                                            b1ff,b2f,b3f,wp1,wp2,wp3,wp4,wcp,
                                            uinv,cnt,uidx);
    k_scan1   <<<U_VOX/256, 256,0,stream>>>(cnt,bsum);
    k_scan2   <<<1,         512,0,stream>>>(bsum);
    k_scan3u  <<<U_VOX/256, 256,0,stream>>>(cnt,bsum,cur,unq,outf);
    k_scatgath<<<N_PTS/256, 256,0,stream>>>(uinv,cat,occ,cur,scat16,svoxS);
    k_fused   <<<NBLK,      256,0,stream>>>(scat16,svoxS,wp1,b1ff,wp2,b2f,
                                            wp3,b3f,wp4,b4,pooled,bpool);
    k_bmerge  <<<U_VOX/16,  256,0,stream>>>(cnt,bsum,cur,bpool,pooled);
    k_head    <<<U_VOX/64,  256,0,stream>>>((unsigned short*)pooled,wcp,bc,occ,uidx,outf);
}